// Round 6
// baseline (302.405 us; speedup 1.0000x reference)
//
#include <hip/hip_runtime.h>

#define B_ 32
#define N_ 4096
#define C_ 16
#define D_ 256
#define NSPLIT 64
#define ROWS   (N_ / NSPLIT)   // 64 rows per block
#define TROWS  8               // rows per tile
#define NTILES (ROWS / TROWS)  // 8 tiles per block

#define AS1(p) ((const __attribute__((address_space(1))) void*)(p))
#define AS3(p) ((__attribute__((address_space(3))) void*)(p))

// ---------------- Stage 1: DMA-pipelined partial sums -> ws ----------------
// Canonical global_load_lds double-buffer: stage tile t+1 (8 rows of v =
// 8 KB + 512 B of r) into LDS while computing tile t from LDS. Thread t owns
// output column d = t: acc[17] scalars (17 VGPR) -> ~40 VGPR total ->
// 8 waves/SIMD, 8 blocks/CU co-resident (17 KB LDS/block). Masks: 2 ballots
// per tile on the LDS r-tile -> wave-uniform SGPRs -> s_cselect-fed FMA.
// Epilogue: plain coalesced partial store (no atomics, no LDS reduction).
__global__ __launch_bounds__(256, 8)
void tf_stage1(const float* __restrict__ r,
               const float* __restrict__ v,
               float* __restrict__ ws) {
    const int b     = blockIdx.x >> 6;           // / NSPLIT
    const int chunk = blockIdx.x & (NSPLIT - 1);
    const int tid   = threadIdx.x;
    const int wave  = tid >> 6;
    const int lane  = tid & 63;

    const float* __restrict__ rb = r + (size_t)b * N_ * C_;
    const float* __restrict__ vp = v + (size_t)b * N_ * D_;
    const int base = chunk * ROWS;

    __shared__ float vbuf[2][TROWS * D_];   // 2 x 8 KiB
    __shared__ float rbuf[2][TROWS * C_];   // 2 x 512 B

    float acc[17];
#pragma unroll
    for (int c = 0; c < 17; ++c) acc[c] = 0.0f;

    // stage tile t into buffer bf: v rows via 16B/lane DMA, r via 4B/lane
#define STAGE_TILE(t, bf)                                                   \
    {                                                                       \
        const int _r0 = (t) * TROWS;                                        \
        _Pragma("unroll")                                                   \
        for (int _i = 0; _i < 2; ++_i) {                                    \
            const int _row = 2 * wave + _i;                                 \
            const float* _g =                                               \
                vp + (size_t)(base + _r0 + _row) * D_ + lane * 4;           \
            __builtin_amdgcn_global_load_lds(                               \
                AS1(_g), AS3(&vbuf[bf][_row * D_]), 16, 0, 0);              \
        }                                                                   \
        if (wave == 0) {                                                    \
            const float* _gr = rb + (size_t)(base + _r0) * C_ + lane;       \
            __builtin_amdgcn_global_load_lds(                               \
                AS1(_gr), AS3(&rbuf[bf][0]), 4, 0, 0);                      \
            __builtin_amdgcn_global_load_lds(                               \
                AS1(_gr + 64), AS3(&rbuf[bf][64]), 4, 0, 0);                \
        }                                                                   \
    }

    STAGE_TILE(0, 0);
    __syncthreads();   // compiler emits vmcnt(0) drain before s_barrier

#pragma unroll
    for (int t = 0; t < NTILES; ++t) {
        const int cur = t & 1;
        if (t + 1 < NTILES) STAGE_TILE(t + 1, cur ^ 1);

        // masks for the 8 rows of this tile: lanes = (row&3, c) pairs
        const unsigned long long bal0 = __ballot(rbuf[cur][lane]      >= 0.5f);
        const unsigned long long bal1 = __ballot(rbuf[cur][64 + lane] >= 0.5f);

#pragma unroll
        for (int rr = 0; rr < TROWS; ++rr) {
            const unsigned mm =
                (unsigned)(((rr < 4) ? bal0 : bal1) >> (16 * (rr & 3))) & 0xFFFFu;
            const float vv = vbuf[cur][rr * D_ + tid];
#pragma unroll
            for (int c = 0; c < 16; ++c) {
                const float m = (mm & (1u << c)) ? 1.0f : 0.0f;  // s_cselect
                acc[c] += vv * m;
            }
            acc[16] += vv * ((mm == 0u) ? 1.0f : 0.0f);  // all-below (rare)
        }
        __syncthreads();   // drains t+1 DMA; protects buffer reuse
    }

    // coalesced partial store: ws[blk][17][256] — thread owns column tid
    float* __restrict__ wsb = ws + (size_t)blockIdx.x * 17 * D_;
#pragma unroll
    for (int c = 0; c < 17; ++c) wsb[c * D_ + tid] = acc[c];
}

// ---------------- Stage 2: reduce 64 chunk-partials per output element -----
__global__ __launch_bounds__(256, 8)
void tf_stage2(const float* __restrict__ ws, float* __restrict__ out) {
    const int b = blockIdx.x / 17;
    const int j = blockIdx.x % 17;
    const int d = threadIdx.x;

    const float* __restrict__ p =
        ws + ((size_t)b * NSPLIT * 17 + j) * D_ + d;
    float s = 0.0f;
#pragma unroll 8
    for (int k = 0; k < NSPLIT; ++k) s += p[(size_t)k * 17 * D_];

    out[((size_t)b * 17 + j) * D_ + d] = s * (1.0f / (float)N_);
}

extern "C" void kernel_launch(void* const* d_in, const int* in_sizes, int n_in,
                              void* d_out, int out_size, void* d_ws, size_t ws_size,
                              hipStream_t stream) {
    const float* r = (const float*)d_in[0];   // (B,N,C) fp32
    const float* v = (const float*)d_in[1];   // (B,N,D) fp32
    float* out = (float*)d_out;               // (B,C+1,D) fp32
    float* ws  = (float*)d_ws;                // 35.7 MB used

    tf_stage1<<<dim3(B_ * NSPLIT), 256, 0, stream>>>(r, v, ws);
    tf_stage2<<<dim3(B_ * 17), 256, 0, stream>>>(ws, out);
    // stage2 writes every out element -> no memset of d_out needed
}

// Round 7
// 201.471 us; speedup vs baseline: 1.5010x; 1.5010x over previous
//
#include <hip/hip_runtime.h>

#define B_ 32
#define N_ 4096
#define C_ 16
#define D_ 256
#define NSPLIT 32
#define ROWS (N_ / NSPLIT)   // 128 rows per block
#define RPW  (ROWS / 4)      // 32 rows per wave
#define NGRP (RPW / 4)       // 8 groups of 4 rows per wave

// ---------------- Stage 1: deep-ring partial sums -> ws (no atomics) -------
// One wave = one full row of D (64 lanes x float4). Ring of 8 rows in
// flight: consume row R, immediately reissue its slot for row R+8 ->
// ~8.25 KB outstanding per wave, 16 waves/CU co-resident (1024 blocks =
// 4 blocks/CU, single dispatch round). Masks: one 64-lane r-load covers a
// 4-row group; ballot -> wave-uniform 16-bit masks in SGPRs; accumulation
// acc[c] += v * m with m in {0,1} (scalar select feeding FMA, no
// divergence). Special (all-below) row -> 17th register accumulator.
__global__ __launch_bounds__(256, 4)
void tf_stage1(const float* __restrict__ r,
               const float* __restrict__ v,
               float* __restrict__ ws) {
    const int b     = blockIdx.x >> 5;           // / NSPLIT
    const int chunk = blockIdx.x & (NSPLIT - 1);
    const int tid   = threadIdx.x;
    const int wave  = tid >> 6;
    const int lane  = tid & 63;
    const int d4    = lane << 2;

    const float* __restrict__ rb = r + (size_t)b * N_ * C_;
    const float* __restrict__ vp = v + (size_t)b * N_ * D_;

    float4 acc[17];                              // [16] = special (all-below)
#pragma unroll
    for (int c = 0; c < 17; ++c) acc[c] = make_float4(0.f, 0.f, 0.f, 0.f);

    const int base = chunk * ROWS + wave * RPW;  // 32 consecutive rows
    const float* __restrict__ rptr = rb + (size_t)base * C_ + lane;
    const float* __restrict__ vptr = vp + (size_t)base * D_ + d4;

    // ---- prologue: r for groups 0,1 first (ballot waits only on these),
    // then the first 8 v rows into the ring
    float rv0 = rptr[0];
    float rv1 = rptr[64];                        // group 1 (rows 4..7)
    float4 ring[8];
#pragma unroll
    for (int s = 0; s < 8; ++s)
        ring[s] = *(const float4*)(vptr + (size_t)s * D_);

#define ACCROW(VV, MASK)                                       \
    {                                                          \
        const unsigned _m = (MASK);                            \
        _Pragma("unroll")                                      \
        for (int c = 0; c < 16; ++c) {                         \
            const float m = (_m & (1u << c)) ? 1.0f : 0.0f;    \
            acc[c].x += (VV).x * m;                            \
            acc[c].y += (VV).y * m;                            \
            acc[c].z += (VV).z * m;                            \
            acc[c].w += (VV).w * m;                            \
        }                                                      \
        const float ms = (_m == 0u) ? 1.0f : 0.0f;             \
        acc[16].x += (VV).x * ms; acc[16].y += (VV).y * ms;    \
        acc[16].z += (VV).z * ms; acc[16].w += (VV).w * ms;    \
    }

#pragma unroll
    for (int g = 0; g < NGRP; ++g) {
        // consume this group's r (loaded 2 groups ago), reissue its slot
        const float rvc = (g & 1) ? rv1 : rv0;
        const unsigned long long bal = __ballot(rvc >= 0.5f);
        if (g + 2 < NGRP) {
            const float rnew = rptr[(size_t)(g + 2) * 64];
            if (g & 1) rv1 = rnew; else rv0 = rnew;
        }
#pragma unroll
        for (int rr = 0; rr < 4; ++rr) {
            const int row  = 4 * g + rr;
            const int slot = row & 7;
            const float4 vv = ring[slot];        // consume (vmcnt wait here)
            if (row + 8 < RPW)                   // reissue slot for row+8
                ring[slot] = *(const float4*)(vptr + (size_t)(row + 8) * D_);
            const unsigned mm = (unsigned)(bal >> (16 * rr)) & 0xFFFFu;
            ACCROW(vv, mm);
        }
    }

    // ---- cross-wave reduction in LDS (wave0 stores, waves 1..3 accumulate)
    __shared__ float4 lds4[17 * 64];    // 17 KiB
    if (wave == 0) {
#pragma unroll
        for (int c = 0; c < 17; ++c) lds4[c * 64 + lane] = acc[c];
    }
    __syncthreads();
    for (int w = 1; w < 4; ++w) {
        if (wave == w) {
#pragma unroll
            for (int c = 0; c < 17; ++c) {
                float4 t = lds4[c * 64 + lane];
                t.x += acc[c].x; t.y += acc[c].y;
                t.z += acc[c].z; t.w += acc[c].w;
                lds4[c * 64 + lane] = t;
            }
        }
        __syncthreads();
    }

    // ---- coalesced partial store: ws[blk][17][256]
    float* __restrict__ wsb = ws + (size_t)blockIdx.x * 17 * D_;
    const float* lf = (const float*)lds4;
#pragma unroll
    for (int c = 0; c < 17; ++c) {
        wsb[c * D_ + tid] = lf[c * 256 + tid];
    }
}

// ---------------- Stage 2: reduce 32 chunk-partials per output element -----
__global__ __launch_bounds__(256, 8)
void tf_stage2(const float* __restrict__ ws, float* __restrict__ out) {
    const int b = blockIdx.x / 17;
    const int j = blockIdx.x % 17;
    const int d = threadIdx.x;

    const float* __restrict__ p =
        ws + ((size_t)b * NSPLIT * 17 + j) * D_ + d;
    float s = 0.0f;
#pragma unroll 8
    for (int k = 0; k < NSPLIT; ++k) s += p[(size_t)k * 17 * D_];

    out[((size_t)b * 17 + j) * D_ + d] = s * (1.0f / (float)N_);
}

extern "C" void kernel_launch(void* const* d_in, const int* in_sizes, int n_in,
                              void* d_out, int out_size, void* d_ws, size_t ws_size,
                              hipStream_t stream) {
    const float* r = (const float*)d_in[0];   // (B,N,C) fp32
    const float* v = (const float*)d_in[1];   // (B,N,D) fp32
    float* out = (float*)d_out;               // (B,C+1,D) fp32
    float* ws  = (float*)d_ws;                // 17.8 MB used

    tf_stage1<<<dim3(B_ * NSPLIT), 256, 0, stream>>>(r, v, ws);
    tf_stage2<<<dim3(B_ * 17), 256, 0, stream>>>(ws, out);
    // stage2 writes every out element -> no memset of d_out needed
}